// Round 1
// baseline (692.658 us; speedup 1.0000x reference)
//
#include <hip/hip_runtime.h>
#include <math.h>

#define NBINS 65536
#define CAP   2048
#define DCH   64

struct Ctrl {
    double thr;       // final threshold (float64, numpy-style lerp)
    int cand_cnt;
    int b0, b1;       // candidate bin range containing ranks i0, i1
    int base0;        // count of elements in bins < b0
    float s0, s1;     // debug: the two order statistics
};

__device__ __forceinline__ int bin_of(float v) {
    int b = (int)(v * (float)NBINS);
    if (b < 0) b = 0;
    if (b >= NBINS) b = NBINS - 1;
    return b;
}

__global__ void k_hist(const float* __restrict__ att, int E, int* __restrict__ hist) {
    int i = blockIdx.x * blockDim.x + threadIdx.x;
    int stride = gridDim.x * blockDim.x;
    for (; i < E; i += stride) {
        atomicAdd(&hist[bin_of(att[i])], 1);
    }
}

// Single block, 1024 threads. Finds bins containing global ranks i0, i1.
__global__ void k_select(const int* __restrict__ hist, Ctrl* ctrl,
                         long long i0, long long i1) {
    __shared__ int partial[1024];
    int t = threadIdx.x;
    int base = t * (NBINS / 1024);   // 64 bins per thread
    int sum = 0;
    for (int j = 0; j < NBINS / 1024; j++) sum += hist[base + j];
    partial[t] = sum;
    __syncthreads();
    // Hillis-Steele inclusive scan over 1024 partials
    for (int off = 1; off < 1024; off <<= 1) {
        int v = (t >= off) ? partial[t - off] : 0;
        __syncthreads();
        partial[t] += v;
        __syncthreads();
    }
    long long c = (long long)(partial[t] - sum);   // exclusive prefix for this chunk
    for (int j = 0; j < NBINS / 1024; j++) {
        int cnt = hist[base + j];
        if (i0 >= c && i0 < c + cnt) { ctrl->b0 = base + j; ctrl->base0 = (int)c; }
        if (i1 >= c && i1 < c + cnt) { ctrl->b1 = base + j; }
        c += cnt;
    }
}

__global__ void k_collect(const float* __restrict__ att, int E,
                          Ctrl* ctrl, float* __restrict__ cand) {
    int b0 = ctrl->b0, b1 = ctrl->b1;
    int i = blockIdx.x * blockDim.x + threadIdx.x;
    int stride = gridDim.x * blockDim.x;
    for (; i < E; i += stride) {
        float v = att[i];
        int b = bin_of(v);
        if (b >= b0 && b <= b1) {
            int idx = atomicAdd(&ctrl->cand_cnt, 1);
            if (idx < CAP) cand[idx] = v;
        }
    }
}

// Single block: exact rank selection among candidates, then numpy-style f64 lerp.
__global__ void k_finalize(Ctrl* ctrl, const float* __restrict__ cand,
                           long long i0, long long i1, double frac) {
    __shared__ float sh[CAP];
    __shared__ float s0s, s1s;
    int n = ctrl->cand_cnt;
    if (n > CAP) n = CAP;
    for (int i = threadIdx.x; i < n; i += blockDim.x) sh[i] = cand[i];
    __syncthreads();
    int r0 = (int)(i0 - (long long)ctrl->base0);
    int r1 = (int)(i1 - (long long)ctrl->base0);
    for (int i = threadIdx.x; i < n; i += blockDim.x) {
        float v = sh[i];
        int rank = 0;
        for (int j = 0; j < n; j++) {
            float u = sh[j];
            rank += (u < v) || (u == v && j < i);   // stable tie-break => unique ranks
        }
        if (rank == r0) s0s = v;
        if (rank == r1) s1s = v;
    }
    __syncthreads();
    if (threadIdx.x == 0) {
        double a = (double)s0s, b = (double)s1s;
        // numpy _lerp, t >= 0.5 branch: b - (b - a) * (1 - t)
        ctrl->thr = b - (b - a) * (1.0 - frac);
        ctrl->s0 = s0s; ctrl->s1 = s1s;
    }
}

// masked att scatter-sum over src (normalization) + kept-degree count over dst
__global__ void k_mask(const float* __restrict__ att, const int* __restrict__ src,
                       const int* __restrict__ dst, int E, const Ctrl* __restrict__ ctrl,
                       float* __restrict__ sums, int* __restrict__ deg) {
    double thr = ctrl->thr;
    int i = blockIdx.x * blockDim.x + threadIdx.x;
    int stride = gridDim.x * blockDim.x;
    for (; i < E; i += stride) {
        float v = att[i];
        if ((double)v > thr) {
            atomicAdd(&sums[src[i]], v);
            atomicAdd(&deg[dst[i]], 1);
        }
    }
}

// Single-block exclusive scan of deg[N] -> rowp[N+1]
__global__ void k_scan(const int* __restrict__ deg, int* __restrict__ rowp, int N) {
    __shared__ int sh[1024];
    __shared__ int carry;
    int t = threadIdx.x;
    if (t == 0) carry = 0;
    __syncthreads();
    for (int base = 0; base < N; base += 1024) {
        int i = base + t;
        int v = (i < N) ? deg[i] : 0;
        sh[t] = v;
        __syncthreads();
        for (int off = 1; off < 1024; off <<= 1) {
            int u = (t >= off) ? sh[t - off] : 0;
            __syncthreads();
            sh[t] += u;
            __syncthreads();
        }
        int incl = sh[t];
        if (i < N) rowp[i] = carry + incl - v;
        __syncthreads();
        if (t == 1023) carry += sh[1023];
        __syncthreads();
    }
    if (t == 0) rowp[N] = carry;
}

__global__ void k_fill(const float* __restrict__ att, const int* __restrict__ src,
                       const int* __restrict__ dst, int E, const Ctrl* __restrict__ ctrl,
                       const float* __restrict__ sums, const int* __restrict__ rowp,
                       int* __restrict__ fillc, int* __restrict__ csr_src,
                       float* __restrict__ csr_w) {
    double thr = ctrl->thr;
    int i = blockIdx.x * blockDim.x + threadIdx.x;
    int stride = gridDim.x * blockDim.x;
    for (; i < E; i += stride) {
        float v = att[i];
        if ((double)v > thr) {
            int s = src[i];
            int dn = dst[i];
            float wv = v / (sums[s] + 1e-16f);
            int pos = rowp[dn] + atomicAdd(&fillc[dn], 1);
            csr_src[pos] = s;
            csr_w[pos] = wv;
        }
    }
}

// One wave (64 lanes = 64 channels) per dst node. Fused RK4 epilogue.
// pass 1: zin=x;   acc  = k;        zout = x + 0.5k
// pass 2:          acc += 2k;       zout = x + 0.5k
// pass 3:          acc += 2k;       zout = x + k
// pass 4:                           zout = x + (acc + k)/6
__global__ __launch_bounds__(256) void k_spmv(
    const int* __restrict__ rowp, const int* __restrict__ csr_src,
    const float* __restrict__ csr_w, const float* __restrict__ zin,
    const float* __restrict__ x, float* __restrict__ acc,
    float* __restrict__ zout, int N, int pass)
{
    int node = blockIdx.x * 4 + threadIdx.y;
    if (node >= N) return;
    int lane = threadIdx.x;
    int beg = rowp[node], end = rowp[node + 1];

    float az0 = 0.f, az1 = 0.f;
    for (int e = beg; e < end; e += 64) {
        int m = end - e;
        if (m > 64) m = 64;
        int s = 0; float wv = 0.f;
        if (lane < m) { s = csr_src[e + lane]; wv = csr_w[e + lane]; }
        int j = 0;
        for (; j + 2 <= m; j += 2) {
            int   sa = __shfl(s,  j,     64);
            int   sb = __shfl(s,  j + 1, 64);
            float wa = __shfl(wv, j,     64);
            float wb = __shfl(wv, j + 1, 64);
            az0 = fmaf(wa, zin[sa * DCH + lane], az0);
            az1 = fmaf(wb, zin[sb * DCH + lane], az1);
        }
        if (j < m) {
            int   sa = __shfl(s,  j, 64);
            float wa = __shfl(wv, j, 64);
            az0 = fmaf(wa, zin[sa * DCH + lane], az0);
        }
    }
    float az = az0 + az1;

    int idx = node * DCH + lane;
    float zi = zin[idx];
    float k  = az - zi;
    float xi = x[idx];
    if (pass == 1)      { acc[idx] = k;                zout[idx] = xi + 0.5f * k; }
    else if (pass == 2) { acc[idx] += 2.f * k;         zout[idx] = xi + 0.5f * k; }
    else if (pass == 3) { acc[idx] += 2.f * k;         zout[idx] = xi + k; }
    else                { zout[idx] = xi + (acc[idx] + k) / 6.0f; }
}

extern "C" void kernel_launch(void* const* d_in, const int* in_sizes, int n_in,
                              void* d_out, int out_size, void* d_ws, size_t ws_size,
                              hipStream_t stream) {
    const float* x   = (const float*)d_in[0];
    const float* att = (const float*)d_in[1];
    const int*   ei  = (const int*)d_in[2];
    const int E = in_sizes[1];
    const int N = in_sizes[0] / DCH;
    const int* src = ei;
    const int* dst = ei + E;

    char* ws = (char*)d_ws;
    size_t off = 0;
    auto alloc = [&](size_t b) { size_t o = off; off += (b + 255) & ~(size_t)255; return o; };
    int*   hist    = (int*)  (ws + alloc((size_t)NBINS * 4));
    Ctrl*  ctrl    = (Ctrl*) (ws + alloc(256));
    float* cand    = (float*)(ws + alloc((size_t)CAP * 4));
    float* sums    = (float*)(ws + alloc((size_t)N * 4));
    int*   deg     = (int*)  (ws + alloc((size_t)N * 4));
    int*   fillc   = (int*)  (ws + alloc((size_t)N * 4));
    int*   rowp    = (int*)  (ws + alloc(((size_t)N + 1) * 4));
    int*   csr_src = (int*)  (ws + alloc((size_t)E * 4));
    float* csr_w   = (float*)(ws + alloc((size_t)E * 4));
    float* zA      = (float*)(ws + alloc((size_t)N * DCH * 4));
    float* acc     = (float*)(ws + alloc((size_t)N * DCH * 4));
    float* out     = (float*)d_out;

    hipMemsetAsync(hist,  0, (size_t)NBINS * 4, stream);
    hipMemsetAsync(ctrl,  0, 256, stream);
    hipMemsetAsync(sums,  0, (size_t)N * 4, stream);
    hipMemsetAsync(deg,   0, (size_t)N * 4, stream);
    hipMemsetAsync(fillc, 0, (size_t)N * 4, stream);

    // numpy-style quantile index arithmetic (float64)
    double q   = 1.0 - 0.8;
    double pos = q * (double)(E - 1);
    long long i0 = (long long)floor(pos);
    double frac  = pos - (double)i0;
    long long i1 = i0 + 1;
    if (i1 > (long long)E - 1) i1 = (long long)E - 1;

    const int tb = 256;
    const int eb = (E + tb - 1) / tb;

    k_hist    <<<eb, tb,   0, stream>>>(att, E, hist);
    k_select  <<<1,  1024, 0, stream>>>(hist, ctrl, i0, i1);
    k_collect <<<eb, tb,   0, stream>>>(att, E, ctrl, cand);
    k_finalize<<<1,  256,  0, stream>>>(ctrl, cand, i0, i1, frac);
    k_mask    <<<eb, tb,   0, stream>>>(att, src, dst, E, ctrl, sums, deg);
    k_scan    <<<1,  1024, 0, stream>>>(deg, rowp, N);
    k_fill    <<<eb, tb,   0, stream>>>(att, src, dst, E, ctrl, sums, rowp, fillc, csr_src, csr_w);

    dim3 blk(64, 4);
    int nb = (N + 3) / 4;
    // z ping-pong: zA <-> d_out (d_out doubles as scratch until pass 4 writes final)
    k_spmv<<<nb, blk, 0, stream>>>(rowp, csr_src, csr_w, x,   x, acc, zA,  N, 1);
    k_spmv<<<nb, blk, 0, stream>>>(rowp, csr_src, csr_w, zA,  x, acc, out, N, 2);
    k_spmv<<<nb, blk, 0, stream>>>(rowp, csr_src, csr_w, out, x, acc, zA,  N, 3);
    k_spmv<<<nb, blk, 0, stream>>>(rowp, csr_src, csr_w, zA,  x, acc, out, N, 4);
}

// Round 2
// 689.182 us; speedup vs baseline: 1.0050x; 1.0050x over previous
//
#include <hip/hip_runtime.h>
#include <math.h>

#define NBINS 65536
#define KH    4        // hist atomic slices
#define KS    8        // node-table atomic slices
#define CAP   2048
#define DCH   64

struct Ctrl {
    double thr;
    int cand_cnt;
    int b0, b1;
    int base0;
    float s0, s1;
};

__device__ __forceinline__ int bin_of(float v) {
    int b = (int)(v * (float)NBINS);
    if (b < 0) b = 0;
    if (b >= NBINS) b = NBINS - 1;
    return b;
}

// ---------- histogram (4-way slice-spread atomics) ----------
__global__ void k_hist(const float* __restrict__ att, int E, int* __restrict__ histT) {
    int i = blockIdx.x * blockDim.x + threadIdx.x;
    int stride = gridDim.x * blockDim.x;
    for (; i < E; i += stride) {
        int k = i & (KH - 1);
        atomicAdd(&histT[k * NBINS + bin_of(att[i])], 1);
    }
}

// Single block, 1024 threads. Finds bins containing global ranks i0, i1.
__global__ void k_select(const int* __restrict__ histT, Ctrl* ctrl,
                         long long i0, long long i1) {
    __shared__ int partial[1024];
    int t = threadIdx.x;
    int base = t * (NBINS / 1024);   // 64 bins per thread
    int sum = 0;
    for (int j = 0; j < NBINS / 1024; j++) {
        int b = base + j;
        int c = 0;
        for (int k = 0; k < KH; k++) c += histT[k * NBINS + b];
        sum += c;
    }
    partial[t] = sum;
    __syncthreads();
    for (int off = 1; off < 1024; off <<= 1) {
        int v = (t >= off) ? partial[t - off] : 0;
        __syncthreads();
        partial[t] += v;
        __syncthreads();
    }
    long long c = (long long)(partial[t] - sum);
    for (int j = 0; j < NBINS / 1024; j++) {
        int b = base + j;
        int cnt = 0;
        for (int k = 0; k < KH; k++) cnt += histT[k * NBINS + b];
        if (i0 >= c && i0 < c + cnt) { ctrl->b0 = b; ctrl->base0 = (int)c; }
        if (i1 >= c && i1 < c + cnt) { ctrl->b1 = b; }
        c += cnt;
    }
}

__global__ void k_collect(const float* __restrict__ att, int E,
                          Ctrl* ctrl, float* __restrict__ cand) {
    int b0 = ctrl->b0, b1 = ctrl->b1;
    int i = blockIdx.x * blockDim.x + threadIdx.x;
    int stride = gridDim.x * blockDim.x;
    for (; i < E; i += stride) {
        float v = att[i];
        int b = bin_of(v);
        if (b >= b0 && b <= b1) {
            int idx = atomicAdd(&ctrl->cand_cnt, 1);
            if (idx < CAP) cand[idx] = v;
        }
    }
}

__global__ void k_finalize(Ctrl* ctrl, const float* __restrict__ cand,
                           long long i0, long long i1, double frac) {
    __shared__ float sh[CAP];
    __shared__ float s0s, s1s;
    int n = ctrl->cand_cnt;
    if (n > CAP) n = CAP;
    for (int i = threadIdx.x; i < n; i += blockDim.x) sh[i] = cand[i];
    __syncthreads();
    int r0 = (int)(i0 - (long long)ctrl->base0);
    int r1 = (int)(i1 - (long long)ctrl->base0);
    for (int i = threadIdx.x; i < n; i += blockDim.x) {
        float v = sh[i];
        int rank = 0;
        for (int j = 0; j < n; j++) {
            float u = sh[j];
            rank += (u < v) || (u == v && j < i);
        }
        if (rank == r0) s0s = v;
        if (rank == r1) s1s = v;
    }
    __syncthreads();
    if (threadIdx.x == 0) {
        double a = (double)s0s, b = (double)s1s;
        ctrl->thr = b - (b - a) * (1.0 - frac);   // numpy _lerp, t>=0.5 branch
        ctrl->s0 = s0s; ctrl->s1 = s1s;
    }
}

// masked sums over src (8-slice float atomics) + kept-deg over dst (8-slice int atomics)
__global__ void k_mask(const float* __restrict__ att, const int* __restrict__ src,
                       const int* __restrict__ dst, int E, int N,
                       const Ctrl* __restrict__ ctrl,
                       float* __restrict__ sumsT, int* __restrict__ degT) {
    double thr = ctrl->thr;
    int i = blockIdx.x * blockDim.x + threadIdx.x;
    int stride = gridDim.x * blockDim.x;
    for (; i < E; i += stride) {
        float v = att[i];
        if ((double)v > thr) {
            int k = i & (KS - 1);
            unsafeAtomicAdd(&sumsT[k * N + src[i]], v);
            atomicAdd(&degT[k * N + dst[i]], 1);
        }
    }
}

// fold 8 sums slices
__global__ void k_reduce(const float* __restrict__ sumsT, float* __restrict__ sums, int N) {
    int n = blockIdx.x * blockDim.x + threadIdx.x;
    if (n >= N) return;
    float s = 0.f;
    for (int k = 0; k < KS; k++) s += sumsT[k * N + n];
    sums[n] = s;
}

// ---------- multi-block exclusive scan over NK = N*KS (dst,k)-ordered counts ----------
// element j corresponds to (dst = j>>3, k = j&7) -> degT[k*N + dst]
#define SCAN_CH 2048

__device__ __forceinline__ int deg_at(const int* degT, int j, int N) {
    return degT[(j & (KS - 1)) * N + (j >> 3)];
}

__global__ void k_scan1(const int* __restrict__ degT, int N, int NK,
                        int* __restrict__ bsum) {
    __shared__ int sh[8];
    int b = blockIdx.x, t = threadIdx.x;
    int j0 = b * SCAN_CH + t * 8;
    int s = 0;
    for (int u = 0; u < 8; u++) {
        int j = j0 + u;
        if (j < NK) s += deg_at(degT, j, N);
    }
    for (int off = 32; off > 0; off >>= 1) s += __shfl_down(s, off, 64);
    if ((t & 63) == 0) sh[t >> 6] = s;
    __syncthreads();
    if (t == 0) {
        int tot = 0;
        for (int w = 0; w < (int)blockDim.x / 64; w++) tot += sh[w];
        bsum[b] = tot;
    }
}

__global__ void k_scan2(const int* __restrict__ bsum, int nb,
                        int* __restrict__ boff, int* __restrict__ rowp, int NK) {
    __shared__ int sh[256];
    int t = threadIdx.x;
    int v = (t < nb) ? bsum[t] : 0;
    sh[t] = v;
    __syncthreads();
    for (int off = 1; off < 256; off <<= 1) {
        int u = (t >= off) ? sh[t - off] : 0;
        __syncthreads();
        sh[t] += u;
        __syncthreads();
    }
    boff[t] = sh[t] - v;   // exclusive
    if (t == 255) rowp[NK] = sh[255];
}

__global__ void k_scan3(const int* __restrict__ degT, int N, int NK,
                        const int* __restrict__ boff, int* __restrict__ rowp) {
    __shared__ int sh[256];
    int b = blockIdx.x, t = threadIdx.x;
    int j0 = b * SCAN_CH + t * 8;
    int v[8];
    int ts = 0;
    for (int u = 0; u < 8; u++) {
        int j = j0 + u;
        v[u] = (j < NK) ? deg_at(degT, j, N) : 0;
        ts += v[u];
    }
    sh[t] = ts;
    __syncthreads();
    for (int off = 1; off < 256; off <<= 1) {
        int u = (t >= off) ? sh[t - off] : 0;
        __syncthreads();
        sh[t] += u;
        __syncthreads();
    }
    int excl = boff[b] + sh[t] - ts;
    for (int u = 0; u < 8; u++) {
        int j = j0 + u;
        if (j < NK) rowp[j] = excl;
        excl += v[u];
    }
}

// place kept edges into dst-contiguous CSR; slice k = i&7 matches k_mask's deg counting
__global__ void k_fill(const float* __restrict__ att, const int* __restrict__ src,
                       const int* __restrict__ dst, int E, int N,
                       const Ctrl* __restrict__ ctrl,
                       const float* __restrict__ sums, const int* __restrict__ rowp,
                       int* __restrict__ fillcT, int* __restrict__ csr_src,
                       float* __restrict__ csr_w) {
    double thr = ctrl->thr;
    int i = blockIdx.x * blockDim.x + threadIdx.x;
    int stride = gridDim.x * blockDim.x;
    for (; i < E; i += stride) {
        float v = att[i];
        if ((double)v > thr) {
            int k = i & (KS - 1);
            int s = src[i];
            int dn = dst[i];
            float wv = v / (sums[s] + 1e-16f);
            int pos = rowp[dn * KS + k] + atomicAdd(&fillcT[k * N + dn], 1);
            csr_src[pos] = s;
            csr_w[pos] = wv;
        }
    }
}

// One wave (64 lanes = 64 channels) per dst node. Fused RK4 epilogue.
__global__ __launch_bounds__(256) void k_spmv(
    const int* __restrict__ rowp, const int* __restrict__ csr_src,
    const float* __restrict__ csr_w, const float* __restrict__ zin,
    const float* __restrict__ x, float* __restrict__ acc,
    float* __restrict__ zout, int N, int pass)
{
    int node = blockIdx.x * 4 + threadIdx.y;
    if (node >= N) return;
    int lane = threadIdx.x;
    int beg = rowp[node * KS], end = rowp[node * KS + KS];

    float az0 = 0.f, az1 = 0.f;
    for (int e = beg; e < end; e += 64) {
        int m = end - e;
        if (m > 64) m = 64;
        int s = 0; float wv = 0.f;
        if (lane < m) { s = csr_src[e + lane]; wv = csr_w[e + lane]; }
        int j = 0;
        for (; j + 2 <= m; j += 2) {
            int   sa = __shfl(s,  j,     64);
            int   sb = __shfl(s,  j + 1, 64);
            float wa = __shfl(wv, j,     64);
            float wb = __shfl(wv, j + 1, 64);
            az0 = fmaf(wa, zin[sa * DCH + lane], az0);
            az1 = fmaf(wb, zin[sb * DCH + lane], az1);
        }
        if (j < m) {
            int   sa = __shfl(s,  j, 64);
            float wa = __shfl(wv, j, 64);
            az0 = fmaf(wa, zin[sa * DCH + lane], az0);
        }
    }
    float az = az0 + az1;

    int idx = node * DCH + lane;
    float zi = zin[idx];
    float k  = az - zi;
    float xi = x[idx];
    if (pass == 1)      { acc[idx] = k;                zout[idx] = xi + 0.5f * k; }
    else if (pass == 2) { acc[idx] += 2.f * k;         zout[idx] = xi + 0.5f * k; }
    else if (pass == 3) { acc[idx] += 2.f * k;         zout[idx] = xi + k; }
    else                { zout[idx] = xi + (acc[idx] + k) / 6.0f; }
}

extern "C" void kernel_launch(void* const* d_in, const int* in_sizes, int n_in,
                              void* d_out, int out_size, void* d_ws, size_t ws_size,
                              hipStream_t stream) {
    const float* x   = (const float*)d_in[0];
    const float* att = (const float*)d_in[1];
    const int*   ei  = (const int*)d_in[2];
    const int E = in_sizes[1];
    const int N = in_sizes[0] / DCH;
    const int NK = N * KS;
    const int* src = ei;
    const int* dst = ei + E;

    char* ws = (char*)d_ws;
    size_t off = 0;
    auto alloc = [&](size_t b) { size_t o = off; off += (b + 255) & ~(size_t)255; return o; };
    // zero-init region: histT | ctrl | sumsT | degT | fillcT  (one memset)
    size_t zbeg = off;
    int*   histT   = (int*)  (ws + alloc((size_t)KH * NBINS * 4));
    Ctrl*  ctrl    = (Ctrl*) (ws + alloc(256));
    float* sumsT   = (float*)(ws + alloc((size_t)KS * N * 4));
    int*   degT    = (int*)  (ws + alloc((size_t)KS * N * 4));
    int*   fillcT  = (int*)  (ws + alloc((size_t)KS * N * 4));
    size_t zlen = off - zbeg;
    float* cand    = (float*)(ws + alloc((size_t)CAP * 4));
    float* sums    = (float*)(ws + alloc((size_t)N * 4));
    int*   rowp    = (int*)  (ws + alloc(((size_t)NK + 1) * 4));
    int*   bsum    = (int*)  (ws + alloc(256 * 4));
    int*   boff    = (int*)  (ws + alloc(256 * 4));
    int*   csr_src = (int*)  (ws + alloc((size_t)E * 4));
    float* csr_w   = (float*)(ws + alloc((size_t)E * 4));
    float* zA      = (float*)(ws + alloc((size_t)N * DCH * 4));
    float* acc     = (float*)(ws + alloc((size_t)N * DCH * 4));
    float* out     = (float*)d_out;

    hipMemsetAsync(ws + zbeg, 0, zlen, stream);

    // numpy-style quantile index arithmetic (float64)
    double q   = 1.0 - 0.8;
    double pos = q * (double)(E - 1);
    long long i0 = (long long)floor(pos);
    double frac  = pos - (double)i0;
    long long i1 = i0 + 1;
    if (i1 > (long long)E - 1) i1 = (long long)E - 1;

    const int tb = 256;
    const int eb = (E + tb - 1) / tb;
    const int nbscan = (NK + SCAN_CH - 1) / SCAN_CH;   // 196 for N=50K

    k_hist    <<<eb, tb,   0, stream>>>(att, E, histT);
    k_select  <<<1,  1024, 0, stream>>>(histT, ctrl, i0, i1);
    k_collect <<<eb, tb,   0, stream>>>(att, E, ctrl, cand);
    k_finalize<<<1,  256,  0, stream>>>(ctrl, cand, i0, i1, frac);
    k_mask    <<<eb, tb,   0, stream>>>(att, src, dst, E, N, ctrl, sumsT, degT);
    k_reduce  <<<(N + 255) / 256, 256, 0, stream>>>(sumsT, sums, N);
    k_scan1   <<<nbscan, 256, 0, stream>>>(degT, N, NK, bsum);
    k_scan2   <<<1, 256, 0, stream>>>(bsum, nbscan, boff, rowp, NK);
    k_scan3   <<<nbscan, 256, 0, stream>>>(degT, N, NK, boff, rowp);
    k_fill    <<<eb, tb,   0, stream>>>(att, src, dst, E, N, ctrl, sums, rowp, fillcT, csr_src, csr_w);

    dim3 blk(64, 4);
    int nb = (N + 3) / 4;
    k_spmv<<<nb, blk, 0, stream>>>(rowp, csr_src, csr_w, x,   x, acc, zA,  N, 1);
    k_spmv<<<nb, blk, 0, stream>>>(rowp, csr_src, csr_w, zA,  x, acc, out, N, 2);
    k_spmv<<<nb, blk, 0, stream>>>(rowp, csr_src, csr_w, out, x, acc, zA,  N, 3);
    k_spmv<<<nb, blk, 0, stream>>>(rowp, csr_src, csr_w, zA,  x, acc, out, N, 4);
}

// Round 3
// 524.587 us; speedup vs baseline: 1.3204x; 1.3138x over previous
//
#include <hip/hip_runtime.h>
#include <math.h>

#define NBINS 65536
#define KH    4        // hist atomic slices
#define KS    8        // node-table atomic slices
#define CAP   2048
#define DCH   64

struct Ctrl {
    double thr;
    int cand_cnt;
    int b0, b1;
    int base0;
    float s0, s1;
};

__device__ __forceinline__ int bin_of(float v) {
    int b = (int)(v * (float)NBINS);
    if (b < 0) b = 0;
    if (b >= NBINS) b = NBINS - 1;
    return b;
}

// ---------- histogram (4-way slice-spread atomics) ----------
__global__ void k_hist(const float* __restrict__ att, int E, int* __restrict__ histT) {
    int i = blockIdx.x * blockDim.x + threadIdx.x;
    int stride = gridDim.x * blockDim.x;
    for (; i < E; i += stride) {
        int k = i & (KH - 1);
        atomicAdd(&histT[k * NBINS + bin_of(att[i])], 1);
    }
}

// 256 blocks x 256 threads: fold slices, emit per-chunk (256-bin) sums
__global__ void k_fold(const int* __restrict__ histT, int* __restrict__ hist,
                       int* __restrict__ csum) {
    __shared__ int sh[4];
    int t = threadIdx.x;
    int b = blockIdx.x * 256 + t;
    int h = 0;
    for (int k = 0; k < KH; k++) h += histT[k * NBINS + b];
    hist[b] = h;
    int s = h;
    for (int off = 32; off > 0; off >>= 1) s += __shfl_down(s, off, 64);
    if ((t & 63) == 0) sh[t >> 6] = s;
    __syncthreads();
    if (t == 0) csum[blockIdx.x] = sh[0] + sh[1] + sh[2] + sh[3];
}

// 1 block x 256 threads: chunk-level scan then bin-level scan -> b0, b1, base0
__global__ void k_pick(const int* __restrict__ hist, const int* __restrict__ csum,
                       Ctrl* ctrl, long long i0, long long i1) {
    __shared__ int sh[256];
    __shared__ int c0s, c1s;
    __shared__ long long e0s, e1s;
    int t = threadIdx.x;
    int v = csum[t];
    sh[t] = v;
    __syncthreads();
    for (int off = 1; off < 256; off <<= 1) {
        int u = (t >= off) ? sh[t - off] : 0;
        __syncthreads();
        sh[t] += u;
        __syncthreads();
    }
    long long excl = (long long)(sh[t] - v);
    if (i0 >= excl && i0 < excl + v) { c0s = t; e0s = excl; }
    if (i1 >= excl && i1 < excl + v) { c1s = t; e1s = excl; }
    __syncthreads();
    int c0 = c0s; long long e0 = e0s;
    int c1 = c1s; long long e1 = e1s;

    // bin-level scan within chunk c0 -> b0, base0
    int hv = hist[c0 * 256 + t];
    sh[t] = hv;
    __syncthreads();
    for (int off = 1; off < 256; off <<= 1) {
        int u = (t >= off) ? sh[t - off] : 0;
        __syncthreads();
        sh[t] += u;
        __syncthreads();
    }
    long long be = e0 + (long long)(sh[t] - hv);
    if (i0 >= be && i0 < be + hv) { ctrl->b0 = c0 * 256 + t; ctrl->base0 = (int)be; }
    __syncthreads();

    // bin-level scan within chunk c1 -> b1
    hv = hist[c1 * 256 + t];
    sh[t] = hv;
    __syncthreads();
    for (int off = 1; off < 256; off <<= 1) {
        int u = (t >= off) ? sh[t - off] : 0;
        __syncthreads();
        sh[t] += u;
        __syncthreads();
    }
    be = e1 + (long long)(sh[t] - hv);
    if (i1 >= be && i1 < be + hv) { ctrl->b1 = c1 * 256 + t; }
}

__global__ void k_collect(const float* __restrict__ att, int E,
                          Ctrl* ctrl, float* __restrict__ cand) {
    int b0 = ctrl->b0, b1 = ctrl->b1;
    int i = blockIdx.x * blockDim.x + threadIdx.x;
    int stride = gridDim.x * blockDim.x;
    for (; i < E; i += stride) {
        float v = att[i];
        int b = bin_of(v);
        if (b >= b0 && b <= b1) {
            int idx = atomicAdd(&ctrl->cand_cnt, 1);
            if (idx < CAP) cand[idx] = v;
        }
    }
}

__global__ void k_finalize(Ctrl* ctrl, const float* __restrict__ cand,
                           long long i0, long long i1, double frac) {
    __shared__ float sh[CAP];
    __shared__ float s0s, s1s;
    int n = ctrl->cand_cnt;
    if (n > CAP) n = CAP;
    for (int i = threadIdx.x; i < n; i += blockDim.x) sh[i] = cand[i];
    __syncthreads();
    int r0 = (int)(i0 - (long long)ctrl->base0);
    int r1 = (int)(i1 - (long long)ctrl->base0);
    for (int i = threadIdx.x; i < n; i += blockDim.x) {
        float v = sh[i];
        int rank = 0;
        for (int j = 0; j < n; j++) {
            float u = sh[j];
            rank += (u < v) || (u == v && j < i);
        }
        if (rank == r0) s0s = v;
        if (rank == r1) s1s = v;
    }
    __syncthreads();
    if (threadIdx.x == 0) {
        double a = (double)s0s, b = (double)s1s;
        ctrl->thr = b - (b - a) * (1.0 - frac);   // numpy _lerp, t>=0.5 branch
        ctrl->s0 = s0s; ctrl->s1 = s1s;
    }
}

// masked sums over src (8-slice float atomics) + kept-deg over dst (8-slice int atomics)
__global__ void k_mask(const float* __restrict__ att, const int* __restrict__ src,
                       const int* __restrict__ dst, int E, int N,
                       const Ctrl* __restrict__ ctrl,
                       float* __restrict__ sumsT, int* __restrict__ degT) {
    double thr = ctrl->thr;
    int i = blockIdx.x * blockDim.x + threadIdx.x;
    int stride = gridDim.x * blockDim.x;
    for (; i < E; i += stride) {
        float v = att[i];
        if ((double)v > thr) {
            int k = i & (KS - 1);
            unsafeAtomicAdd(&sumsT[k * N + src[i]], v);
            atomicAdd(&degT[k * N + dst[i]], 1);
        }
    }
}

// fold 8 sums slices
__global__ void k_reduce(const float* __restrict__ sumsT, float* __restrict__ sums, int N) {
    int n = blockIdx.x * blockDim.x + threadIdx.x;
    if (n >= N) return;
    float s = 0.f;
    for (int k = 0; k < KS; k++) s += sumsT[k * N + n];
    sums[n] = s;
}

// ---------- multi-block exclusive scan over NK = N*KS (dst,k)-ordered counts ----------
#define SCAN_CH 2048

__device__ __forceinline__ int deg_at(const int* degT, int j, int N) {
    return degT[(j & (KS - 1)) * N + (j >> 3)];
}

__global__ void k_scan1(const int* __restrict__ degT, int N, int NK,
                        int* __restrict__ bsum) {
    __shared__ int sh[8];
    int b = blockIdx.x, t = threadIdx.x;
    int j0 = b * SCAN_CH + t * 8;
    int s = 0;
    for (int u = 0; u < 8; u++) {
        int j = j0 + u;
        if (j < NK) s += deg_at(degT, j, N);
    }
    for (int off = 32; off > 0; off >>= 1) s += __shfl_down(s, off, 64);
    if ((t & 63) == 0) sh[t >> 6] = s;
    __syncthreads();
    if (t == 0) {
        int tot = 0;
        for (int w = 0; w < (int)blockDim.x / 64; w++) tot += sh[w];
        bsum[b] = tot;
    }
}

__global__ void k_scan2(const int* __restrict__ bsum, int nb,
                        int* __restrict__ boff, int* __restrict__ rowp, int NK) {
    __shared__ int sh[256];
    int t = threadIdx.x;
    int v = (t < nb) ? bsum[t] : 0;
    sh[t] = v;
    __syncthreads();
    for (int off = 1; off < 256; off <<= 1) {
        int u = (t >= off) ? sh[t - off] : 0;
        __syncthreads();
        sh[t] += u;
        __syncthreads();
    }
    boff[t] = sh[t] - v;   // exclusive
    if (t == 255) rowp[NK] = sh[255];
}

__global__ void k_scan3(const int* __restrict__ degT, int N, int NK,
                        const int* __restrict__ boff, int* __restrict__ rowp) {
    __shared__ int sh[256];
    int b = blockIdx.x, t = threadIdx.x;
    int j0 = b * SCAN_CH + t * 8;
    int v[8];
    int ts = 0;
    for (int u = 0; u < 8; u++) {
        int j = j0 + u;
        v[u] = (j < NK) ? deg_at(degT, j, N) : 0;
        ts += v[u];
    }
    sh[t] = ts;
    __syncthreads();
    for (int off = 1; off < 256; off <<= 1) {
        int u = (t >= off) ? sh[t - off] : 0;
        __syncthreads();
        sh[t] += u;
        __syncthreads();
    }
    int excl = boff[b] + sh[t] - ts;
    for (int u = 0; u < 8; u++) {
        int j = j0 + u;
        if (j < NK) rowp[j] = excl;
        excl += v[u];
    }
}

// place kept edges into dst-contiguous CSR; slice k = i&7 matches k_mask's deg counting
__global__ void k_fill(const float* __restrict__ att, const int* __restrict__ src,
                       const int* __restrict__ dst, int E, int N,
                       const Ctrl* __restrict__ ctrl,
                       const float* __restrict__ sums, const int* __restrict__ rowp,
                       int* __restrict__ fillcT, int* __restrict__ csr_src,
                       float* __restrict__ csr_w) {
    double thr = ctrl->thr;
    int i = blockIdx.x * blockDim.x + threadIdx.x;
    int stride = gridDim.x * blockDim.x;
    for (; i < E; i += stride) {
        float v = att[i];
        if ((double)v > thr) {
            int k = i & (KS - 1);
            int s = src[i];
            int dn = dst[i];
            float wv = v / (sums[s] + 1e-16f);
            int pos = rowp[dn * KS + k] + atomicAdd(&fillcT[k * N + dn], 1);
            csr_src[pos] = s;
            csr_w[pos] = wv;
        }
    }
}

// One wave (64 lanes = 64 channels) per dst node. Fused RK4 epilogue.
__global__ __launch_bounds__(256) void k_spmv(
    const int* __restrict__ rowp, const int* __restrict__ csr_src,
    const float* __restrict__ csr_w, const float* __restrict__ zin,
    const float* __restrict__ x, float* __restrict__ acc,
    float* __restrict__ zout, int N, int pass)
{
    int node = blockIdx.x * 4 + threadIdx.y;
    if (node >= N) return;
    int lane = threadIdx.x;
    int beg = rowp[node * KS], end = rowp[node * KS + KS];

    float az0 = 0.f, az1 = 0.f, az2 = 0.f, az3 = 0.f;
    for (int e = beg; e < end; e += 64) {
        int m = end - e;
        if (m > 64) m = 64;
        int s = 0; float wv = 0.f;
        if (lane < m) { s = csr_src[e + lane]; wv = csr_w[e + lane]; }
        int j = 0;
        for (; j + 4 <= m; j += 4) {
            int   sa = __shfl(s,  j,     64);
            int   sb = __shfl(s,  j + 1, 64);
            int   sc = __shfl(s,  j + 2, 64);
            int   sd = __shfl(s,  j + 3, 64);
            float wa = __shfl(wv, j,     64);
            float wb = __shfl(wv, j + 1, 64);
            float wc = __shfl(wv, j + 2, 64);
            float wd = __shfl(wv, j + 3, 64);
            az0 = fmaf(wa, zin[sa * DCH + lane], az0);
            az1 = fmaf(wb, zin[sb * DCH + lane], az1);
            az2 = fmaf(wc, zin[sc * DCH + lane], az2);
            az3 = fmaf(wd, zin[sd * DCH + lane], az3);
        }
        for (; j < m; j++) {
            int   sa = __shfl(s,  j, 64);
            float wa = __shfl(wv, j, 64);
            az0 = fmaf(wa, zin[sa * DCH + lane], az0);
        }
    }
    float az = (az0 + az1) + (az2 + az3);

    int idx = node * DCH + lane;
    float zi = zin[idx];
    float k  = az - zi;
    float xi = x[idx];
    if (pass == 1)      { acc[idx] = k;                zout[idx] = xi + 0.5f * k; }
    else if (pass == 2) { acc[idx] += 2.f * k;         zout[idx] = xi + 0.5f * k; }
    else if (pass == 3) { acc[idx] += 2.f * k;         zout[idx] = xi + k; }
    else                { zout[idx] = xi + (acc[idx] + k) / 6.0f; }
}

extern "C" void kernel_launch(void* const* d_in, const int* in_sizes, int n_in,
                              void* d_out, int out_size, void* d_ws, size_t ws_size,
                              hipStream_t stream) {
    const float* x   = (const float*)d_in[0];
    const float* att = (const float*)d_in[1];
    const int*   ei  = (const int*)d_in[2];
    const int E = in_sizes[1];
    const int N = in_sizes[0] / DCH;
    const int NK = N * KS;
    const int* src = ei;
    const int* dst = ei + E;

    char* ws = (char*)d_ws;
    size_t off = 0;
    auto alloc = [&](size_t b) { size_t o = off; off += (b + 255) & ~(size_t)255; return o; };
    // zero-init region: histT | ctrl | sumsT | degT | fillcT  (one memset)
    size_t zbeg = off;
    int*   histT   = (int*)  (ws + alloc((size_t)KH * NBINS * 4));
    Ctrl*  ctrl    = (Ctrl*) (ws + alloc(256));
    float* sumsT   = (float*)(ws + alloc((size_t)KS * N * 4));
    int*   degT    = (int*)  (ws + alloc((size_t)KS * N * 4));
    int*   fillcT  = (int*)  (ws + alloc((size_t)KS * N * 4));
    size_t zlen = off - zbeg;
    int*   hist    = (int*)  (ws + alloc((size_t)NBINS * 4));
    int*   csum    = (int*)  (ws + alloc(256 * 4));
    float* cand    = (float*)(ws + alloc((size_t)CAP * 4));
    float* sums    = (float*)(ws + alloc((size_t)N * 4));
    int*   rowp    = (int*)  (ws + alloc(((size_t)NK + 1) * 4));
    int*   bsum    = (int*)  (ws + alloc(256 * 4));
    int*   boff    = (int*)  (ws + alloc(256 * 4));
    int*   csr_src = (int*)  (ws + alloc((size_t)E * 4));
    float* csr_w   = (float*)(ws + alloc((size_t)E * 4));
    float* zA      = (float*)(ws + alloc((size_t)N * DCH * 4));
    float* acc     = (float*)(ws + alloc((size_t)N * DCH * 4));
    float* out     = (float*)d_out;

    hipMemsetAsync(ws + zbeg, 0, zlen, stream);

    // numpy-style quantile index arithmetic (float64)
    double q   = 1.0 - 0.8;
    double pos = q * (double)(E - 1);
    long long i0 = (long long)floor(pos);
    double frac  = pos - (double)i0;
    long long i1 = i0 + 1;
    if (i1 > (long long)E - 1) i1 = (long long)E - 1;

    const int tb = 256;
    const int eb = (E + tb - 1) / tb;
    const int nbscan = (NK + SCAN_CH - 1) / SCAN_CH;

    k_hist    <<<eb, tb,   0, stream>>>(att, E, histT);
    k_fold    <<<NBINS / 256, 256, 0, stream>>>(histT, hist, csum);
    k_pick    <<<1, 256, 0, stream>>>(hist, csum, ctrl, i0, i1);
    k_collect <<<eb, tb,   0, stream>>>(att, E, ctrl, cand);
    k_finalize<<<1,  256,  0, stream>>>(ctrl, cand, i0, i1, frac);
    k_mask    <<<eb, tb,   0, stream>>>(att, src, dst, E, N, ctrl, sumsT, degT);
    k_reduce  <<<(N + 255) / 256, 256, 0, stream>>>(sumsT, sums, N);
    k_scan1   <<<nbscan, 256, 0, stream>>>(degT, N, NK, bsum);
    k_scan2   <<<1, 256, 0, stream>>>(bsum, nbscan, boff, rowp, NK);
    k_scan3   <<<nbscan, 256, 0, stream>>>(degT, N, NK, boff, rowp);
    k_fill    <<<eb, tb,   0, stream>>>(att, src, dst, E, N, ctrl, sums, rowp, fillcT, csr_src, csr_w);

    dim3 blk(64, 4);
    int nb = (N + 3) / 4;
    k_spmv<<<nb, blk, 0, stream>>>(rowp, csr_src, csr_w, x,   x, acc, zA,  N, 1);
    k_spmv<<<nb, blk, 0, stream>>>(rowp, csr_src, csr_w, zA,  x, acc, out, N, 2);
    k_spmv<<<nb, blk, 0, stream>>>(rowp, csr_src, csr_w, out, x, acc, zA,  N, 3);
    k_spmv<<<nb, blk, 0, stream>>>(rowp, csr_src, csr_w, zA,  x, acc, out, N, 4);
}